// Round 5
// baseline (2830.585 us; speedup 1.0000x reference)
//
#include <hip/hip_runtime.h>

#define NODES 100000
#define EDGES 3200000
#define D 128
#define NBUCKET ((NODES + 255) / 256)    // 391 dst-buckets of 256 nodes
#define NBUCKP 392                       // padded even for pairwise scan
#define CH 4096                          // edges per binning block
#define NB_BIN ((EDGES + CH - 1) / CH)   // 782 binning blocks
#define CAP 10240                        // static per-bucket slot capacity (actual max ~8550)

typedef unsigned short us8 __attribute__((ext_vector_type(8)));
typedef _Float16 half8 __attribute__((ext_vector_type(8)));
typedef _Float16 h2 __attribute__((ext_vector_type(2)));
typedef float f32x4 __attribute__((ext_vector_type(4)));

__device__ __forceinline__ unsigned short f32_to_f16_bits(float f) {
    return __builtin_bit_cast(unsigned short, (_Float16)f);
}
__device__ __forceinline__ h2 uh2(unsigned u) {
    return __builtin_bit_cast(h2, u);
}

// ---------------- w prep: fp32 [128][128] -> fp16 in B-fragment order -------
__global__ __launch_bounds__(256) void wprep(const float* __restrict__ w,
                                             unsigned short* __restrict__ wt) {
    int i = blockIdx.x * 256 + threadIdx.x;
    if (i >= 16384) return;
    int j  = i & 7;
    int l  = (i >> 3) & 63;
    int c  = (i >> 9) & 3;
    int ct = i >> 11;
    int k   = 32 * c + ((l >> 4) << 3) + j;
    int col = (ct << 4) + (l & 15);
    wt[i] = f32_to_f16_bits(w[k * D + col]);
}

// ---------------- GEMM via MFMA: h = fp16(x) @ fp16(w) ----------------------
// hb written PLANE-SPLIT: hb[plane][node][64] fp16, plane = ch>>6, so each
// bucket_agg plane-visit gathers exactly one 128-B line per edge.
__global__ __launch_bounds__(256) void gemm_mfma(const float* __restrict__ x,
                                                 const unsigned short* __restrict__ wt,
                                                 unsigned short* __restrict__ hb) {
    __shared__ unsigned short wl[16384];   // 32 KB
    const int tid = threadIdx.x;
    for (int i = tid; i < 2048; i += 256)
        ((us8*)wl)[i] = ((const us8*)wt)[i];
    __syncthreads();

    const int wave = tid >> 6, lane = tid & 63;
    const long r0 = ((long)blockIdx.x * 4 + wave) * 16;
    if (r0 >= NODES) return;
    const int m = lane & 15, q = lane >> 4;
    const float* xr = x + (r0 + m) * D;

    f32x4 acc[8];
#pragma unroll
    for (int ct = 0; ct < 8; ct++) acc[ct] = (f32x4){0.f, 0.f, 0.f, 0.f};

#pragma unroll
    for (int c = 0; c < 4; c++) {
        const int k0 = 32 * c + 8 * q;
        float4 xa = *(const float4*)(xr + k0);
        float4 xb = *(const float4*)(xr + k0 + 4);
        half8 a;
        a[0] = (_Float16)xa.x;
        a[1] = (_Float16)xa.y;
        a[2] = (_Float16)xa.z;
        a[3] = (_Float16)xa.w;
        a[4] = (_Float16)xb.x;
        a[5] = (_Float16)xb.y;
        a[6] = (_Float16)xb.z;
        a[7] = (_Float16)xb.w;
#pragma unroll
        for (int ct = 0; ct < 8; ct++) {
            half8 bfr = *(const half8*)&wl[(((ct << 2) + c) * 64 + lane) * 8];
            acc[ct] = __builtin_amdgcn_mfma_f32_16x16x32_f16(a, bfr, acc[ct], 0, 0, 0);
        }
    }

    // C/D: col = lane&15, row = (lane>>4)*4 + reg. ch = ct*16+m -> plane ct>>2.
#pragma unroll
    for (int ct = 0; ct < 8; ct++) {
        unsigned short* hp = hb + (size_t)(ct >> 2) * (NODES * 64) + ((ct & 3) * 16 + m);
#pragma unroll
        for (int r = 0; r < 4; r++) {
            int row = q * 4 + r;
            hp[(r0 + row) * 64] = f32_to_f16_bits(acc[ct][r]);
        }
    }
}

// ---------------- pass 1: in-LDS counting sort by bucket, coalesced writeout
// bcur holds per-bucket COUNTS (zeroed by memset); global slot = b*CAP + cnt.
// pk = (fp16_bits(val) << 17) | src   (val in [0,1) -> bits < 0x3C00 < 2^15)
__global__ __launch_bounds__(256) void bin_pass1(const int* __restrict__ esrc,
                                                 const int* __restrict__ edst,
                                                 const float* __restrict__ eval,
                                                 int* __restrict__ bcur,
                                                 int2* __restrict__ tmp) {
    __shared__ int2 sed[CH];          // 32 KB sorted (pk, dst)
    __shared__ int hist[NBUCKP];
    __shared__ int basel[NBUCKP];
    __shared__ int lcur[NBUCKP];
    __shared__ int gbase[NBUCKP];
    __shared__ int wsum[4];
    const int tid = threadIdx.x;
    const long e0 = (long)blockIdx.x * CH;
    const int n = (int)((EDGES - e0 < CH) ? (EDGES - e0) : CH);

    for (int bk = tid; bk < NBUCKP; bk += 256) { hist[bk] = 0; lcur[bk] = 0; }
    __syncthreads();
    for (int i = tid; i < n; i += 256)
        atomicAdd(&hist[edst[e0 + i] >> 8], 1);
    __syncthreads();

    // pairwise exclusive scan of 392 bins: thread t owns bins 2t, 2t+1
    int h0 = 0, h1 = 0;
    if (tid < 196) { h0 = hist[2 * tid]; h1 = hist[2 * tid + 1]; }
    int s = h0 + h1;
    int lane = tid & 63, wid = tid >> 6;
    int sc = s;
#pragma unroll
    for (int off = 1; off < 64; off <<= 1) {
        int t = __shfl_up(sc, off, 64);
        if (lane >= off) sc += t;
    }
    if (lane == 63) wsum[wid] = sc;
    __syncthreads();
    int wb = 0;
    for (int w2 = 0; w2 < wid; w2++) wb += wsum[w2];
    int excl = wb + sc - s;
    if (tid < 196) { basel[2 * tid] = excl; basel[2 * tid + 1] = excl + h0; }
    for (int bk = tid; bk < NBUCKET; bk += 256) {
        int c = hist[bk];
        if (c > 0) gbase[bk] = bk * CAP + atomicAdd(&bcur[bk], c);
    }
    __syncthreads();

    // scatter into LDS, sorted by bucket
    for (int i = tid; i < n; i += 256) {
        long e = e0 + i;
        int dst = edst[e];
        unsigned hv = (unsigned)f32_to_f16_bits(eval[e]);
        unsigned pk = (hv << 17) | (unsigned)esrc[e];
        int bk = dst >> 8;
        int lp = basel[bk] + atomicAdd(&lcur[bk], 1);
        sed[lp] = make_int2((int)pk, dst);
    }
    __syncthreads();

    // coalesced write-out: consecutive i -> consecutive global within runs
    for (int i = tid; i < n; i += 256) {
        int2 t = sed[i];
        int bk = t.y >> 8;
        tmp[gbase[bk] + (i - basel[bk])] = t;
    }
}

// ---------------- bucket aggregation: block = (bucket, plane) ---------------
// Consumes bucket-sorted tmp directly; per-node CSR / epack / pass2 deleted.
// acc[64ch][257] fp32 in LDS (stride 257 => atomic banks = (ch + d8) & 31,
// ~2-way conflicts). ds_add_f32 is native; fp32 accumulation (better than the
// previous fp16 register chains). 8 waves x 4-slot unroll = 32 gathers in
// flight per wave-iter; 2 blocks/CU (64.3 KB LDS) = 16 waves/CU.
__global__ __launch_bounds__(512) void bucket_agg(const int* __restrict__ bcur,
                                                  const int2* __restrict__ tmp,
                                                  const unsigned short* __restrict__ hb,
                                                  const float* __restrict__ bias,
                                                  float* __restrict__ out) {
    __shared__ float acc[64 * 257];   // 65792 B
    const int tid = threadIdx.x;
    const int b = blockIdx.x, plane = blockIdx.y;
    const int n = bcur[b];
    const long base = (long)b * CAP;
    const int wv = tid >> 6, lane = tid & 63;
    const int sub = lane >> 3, j = lane & 7;     // 8 subs x 8 lanes; lane j covers ch 8j..8j+7
    const unsigned short* hp = hb + (size_t)plane * (NODES * 64) + j * 8;

    for (int i = tid; i < 64 * 257; i += 512) acc[i] = 0.f;
    __syncthreads();

    // 8 waves x 4 slots x 8 subs = 256 edges per block-iter
    for (int ib = wv * 32; ib < n; ib += 256) {
        int2 t[4];
#pragma unroll
        for (int u = 0; u < 4; u++) {
            int idx = ib + u * 8 + sub;
            t[u] = (idx < n) ? tmp[base + idx] : make_int2(0, 0);  // pk=0 -> val=0
        }
        uint4 r[4];
        float vf[4];
        int d8[4];
#pragma unroll
        for (int u = 0; u < 4; u++) {
            unsigned pk = (unsigned)t[u].x;
            d8[u] = t[u].y & 255;
            vf[u] = (float)__builtin_bit_cast(_Float16, (unsigned short)(pk >> 17));
            unsigned src = pk & 0x1FFFFu;
            r[u] = *(const uint4*)(hp + (size_t)src * 64);   // 16 B of the 128-B row
        }
#pragma unroll
        for (int u = 0; u < 4; u++) {
            float* ap = &acc[(j * 8) * 257 + d8[u]];
            h2 h01 = uh2(r[u].x), h23 = uh2(r[u].y);
            h2 h45 = uh2(r[u].z), h67 = uh2(r[u].w);
            atomicAdd(ap + 0 * 257, vf[u] * (float)h01[0]);
            atomicAdd(ap + 1 * 257, vf[u] * (float)h01[1]);
            atomicAdd(ap + 2 * 257, vf[u] * (float)h23[0]);
            atomicAdd(ap + 3 * 257, vf[u] * (float)h23[1]);
            atomicAdd(ap + 4 * 257, vf[u] * (float)h45[0]);
            atomicAdd(ap + 5 * 257, vf[u] * (float)h45[1]);
            atomicAdd(ap + 6 * 257, vf[u] * (float)h67[0]);
            atomicAdd(ap + 7 * 257, vf[u] * (float)h67[1]);
        }
    }
    __syncthreads();

    // epilogue: lane = ch; per instr 64 lanes write 256 contiguous bytes of out
    float bch = bias[plane * 64 + lane];
    for (int nd = wv; nd < 256; nd += 8) {
        int node = (b << 8) + nd;
        if (node < NODES) {
            float v = acc[lane * 257 + nd] + bch;   // banks (lane+nd)&31: conflict-free
            out[(size_t)node * D + plane * 64 + lane] = fmaxf(v, 0.f);
        }
    }
}

extern "C" void kernel_launch(void* const* d_in, const int* in_sizes, int n_in,
                              void* d_out, int out_size, void* d_ws, size_t ws_size,
                              hipStream_t stream) {
    const float* x    = (const float*)d_in[0];
    const int*   esrc = (const int*)  d_in[1];
    const int*   edst = (const int*)  d_in[2];
    const float* eval = (const float*)d_in[3];
    const float* w    = (const float*)d_in[4];
    const float* b    = (const float*)d_in[5];
    float* out = (float*)d_out;

    // workspace layout (bytes), total 57,665,536
    char* ws = (char*)d_ws;
    const size_t OFF_H    = 0;                       // 25,600,000 (fp16 h, 2 planes)
    const size_t OFF_WT   = 25600000;                // 32,768
    const size_t OFF_BCUR = OFF_WT   + 32768;        // 2,048
    const size_t OFF_TMP  = OFF_BCUR + 2048;         // 391*CAP*8 = 32,030,720

    unsigned short* hb   = (unsigned short*)(ws + OFF_H);
    unsigned short* wt   = (unsigned short*)(ws + OFF_WT);
    int*            bcur = (int*)           (ws + OFF_BCUR);
    int2*           tmp  = (int2*)          (ws + OFF_TMP);

    hipMemsetAsync(bcur, 0, NBUCKET * sizeof(int), stream);
    wprep<<<64, 256, 0, stream>>>(w, wt);
    gemm_mfma<<<(NODES + 63) / 64, 256, 0, stream>>>(x, wt, hb);
    bin_pass1<<<NB_BIN, 256, 0, stream>>>(esrc, edst, eval, bcur, tmp);
    bucket_agg<<<dim3(NBUCKET, 2), 512, 0, stream>>>(bcur, tmp, hb, b, out);
}

// Round 6
// 293.414 us; speedup vs baseline: 9.6471x; 9.6471x over previous
//
#include <hip/hip_runtime.h>

#define NODES 100000
#define EDGES 3200000
#define D 128
#define NBUCKET ((NODES + 255) / 256)    // 391 dst-buckets of 256 nodes
#define NBUCKP 392                       // padded even for pairwise scan
#define CH 4096                          // edges per binning block
#define NB_BIN ((EDGES + CH - 1) / CH)   // 782 binning blocks
#define CAP 10240                        // static per-bucket slot capacity (actual max ~8550)

typedef unsigned short us8 __attribute__((ext_vector_type(8)));
typedef _Float16 half8 __attribute__((ext_vector_type(8)));
typedef _Float16 h2 __attribute__((ext_vector_type(2)));
typedef float f32x4 __attribute__((ext_vector_type(4)));

__device__ __forceinline__ unsigned short f32_to_f16_bits(float f) {
    return __builtin_bit_cast(unsigned short, (_Float16)f);
}
__device__ __forceinline__ h2 uh2(unsigned u) {
    return __builtin_bit_cast(h2, u);
}

// ---------------- w prep: fp32 [128][128] -> fp16 in B-fragment order -------
__global__ __launch_bounds__(256) void wprep(const float* __restrict__ w,
                                             unsigned short* __restrict__ wt) {
    int i = blockIdx.x * 256 + threadIdx.x;
    if (i >= 16384) return;
    int j  = i & 7;
    int l  = (i >> 3) & 63;
    int c  = (i >> 9) & 3;
    int ct = i >> 11;
    int k   = 32 * c + ((l >> 4) << 3) + j;
    int col = (ct << 4) + (l & 15);
    wt[i] = f32_to_f16_bits(w[k * D + col]);
}

// ---------------- GEMM via MFMA: h = fp16(x) @ fp16(w), hb fp16 row-major ---
__global__ __launch_bounds__(256) void gemm_mfma(const float* __restrict__ x,
                                                 const unsigned short* __restrict__ wt,
                                                 unsigned short* __restrict__ hb) {
    __shared__ unsigned short wl[16384];   // 32 KB
    const int tid = threadIdx.x;
    for (int i = tid; i < 2048; i += 256)
        ((us8*)wl)[i] = ((const us8*)wt)[i];
    __syncthreads();

    const int wave = tid >> 6, lane = tid & 63;
    const long r0 = ((long)blockIdx.x * 4 + wave) * 16;
    if (r0 >= NODES) return;
    const int m = lane & 15, q = lane >> 4;
    const float* xr = x + (r0 + m) * D;

    f32x4 acc[8];
#pragma unroll
    for (int ct = 0; ct < 8; ct++) acc[ct] = (f32x4){0.f, 0.f, 0.f, 0.f};

#pragma unroll
    for (int c = 0; c < 4; c++) {
        const int k0 = 32 * c + 8 * q;
        float4 xa = *(const float4*)(xr + k0);
        float4 xb = *(const float4*)(xr + k0 + 4);
        half8 a;
        a[0] = (_Float16)xa.x;
        a[1] = (_Float16)xa.y;
        a[2] = (_Float16)xa.z;
        a[3] = (_Float16)xa.w;
        a[4] = (_Float16)xb.x;
        a[5] = (_Float16)xb.y;
        a[6] = (_Float16)xb.z;
        a[7] = (_Float16)xb.w;
#pragma unroll
        for (int ct = 0; ct < 8; ct++) {
            half8 bfr = *(const half8*)&wl[(((ct << 2) + c) * 64 + lane) * 8];
            acc[ct] = __builtin_amdgcn_mfma_f32_16x16x32_f16(a, bfr, acc[ct], 0, 0, 0);
        }
    }

    // C/D: col = lane&15, row = (lane>>4)*4 + reg
#pragma unroll
    for (int ct = 0; ct < 8; ct++) {
#pragma unroll
        for (int r = 0; r < 4; r++) {
            int row = q * 4 + r;
            hb[(r0 + row) * D + ct * 16 + m] = f32_to_f16_bits(acc[ct][r]);
        }
    }
}

// ---------------- pass 1: SINGLE global read, register-staged counting sort -
// 512 threads x 8 edges in registers; hist from regs; LDS scatter; coalesced
// writeout. bcur holds per-bucket COUNTS (zeroed by memset).
// pk = (fp16_bits(val) << 17) | src   (val in [0,1) -> bits < 0x3C00 < 2^15)
__global__ __launch_bounds__(512) void bin_pass1(const int* __restrict__ esrc,
                                                 const int* __restrict__ edst,
                                                 const float* __restrict__ eval,
                                                 int* __restrict__ bcur,
                                                 int2* __restrict__ tmp) {
    __shared__ int2 sed[CH];          // 32768 B sorted (pk, dst)
    __shared__ int hist[NBUCKP];
    __shared__ int basel[NBUCKP];
    __shared__ int lcur[NBUCKP];
    __shared__ int gbase[NBUCKP];
    __shared__ int wsum[8];
    const int tid = threadIdx.x;
    const long e0 = (long)blockIdx.x * CH;
    const int n = (int)((EDGES - e0 < CH) ? (EDGES - e0) : CH);

    for (int bk = tid; bk < NBUCKP; bk += 512) { hist[bk] = 0; lcur[bk] = 0; }
    __syncthreads();

    // one coalesced pass: stage 8 edges/thread in registers + histogram
    unsigned pk[8];
    int ds[8];
#pragma unroll
    for (int u = 0; u < 8; u++) {
        int i = tid + u * 512;
        if (i < n) {
            long e = e0 + i;
            int dst = edst[e];
            unsigned hv = (unsigned)f32_to_f16_bits(eval[e]);
            pk[u] = (hv << 17) | (unsigned)esrc[e];
            ds[u] = dst;
            atomicAdd(&hist[dst >> 8], 1);
        } else {
            ds[u] = -1;
        }
    }
    __syncthreads();

    // pairwise exclusive scan of 392 bins: thread t<196 owns bins 2t, 2t+1
    int h0 = 0, h1 = 0;
    if (tid < 196) { h0 = hist[2 * tid]; h1 = hist[2 * tid + 1]; }
    int s = h0 + h1;
    int lane = tid & 63, wid = tid >> 6;
    int sc = s;
#pragma unroll
    for (int off = 1; off < 64; off <<= 1) {
        int t = __shfl_up(sc, off, 64);
        if (lane >= off) sc += t;
    }
    if (lane == 63) wsum[wid] = sc;
    __syncthreads();
    int wb = 0;
    for (int w2 = 0; w2 < wid && w2 < 4; w2++) wb += wsum[w2];
    int excl = wb + sc - s;
    if (tid < 196) { basel[2 * tid] = excl; basel[2 * tid + 1] = excl + h0; }
    for (int bk = tid; bk < NBUCKET; bk += 512) {
        int c = hist[bk];
        if (c > 0) gbase[bk] = bk * CAP + atomicAdd(&bcur[bk], c);
    }
    __syncthreads();

    // scatter from registers into LDS, sorted by bucket
#pragma unroll
    for (int u = 0; u < 8; u++) {
        if (ds[u] >= 0) {
            int bk = ds[u] >> 8;
            int lp = basel[bk] + atomicAdd(&lcur[bk], 1);
            sed[lp] = make_int2((int)pk[u], ds[u]);
        }
    }
    __syncthreads();

    // coalesced write-out: consecutive i -> consecutive global within runs
    for (int i = tid; i < n; i += 512) {
        int2 t = sed[i];
        int bk = t.y >> 8;
        tmp[gbase[bk] + (i - basel[bk])] = t;
    }
}

// ---------------- pass 2: LDS-staged bucket -> per-node CSR + in-place epack
// 512 threads (24 waves/CU at 3 blocks). epack ALIASES tmp: bucket b's epack
// slots (u32 index 2*b*CAP + j) occupy the front half of its own int2 region;
// whole bucket staged to LDS before any write -> no hazard.
// rpd[node] = ((2*b*CAP + excl) << 8) | degree.
__global__ __launch_bounds__(512) void bin_pass2(const int* __restrict__ bcur,
                                                 const int2* __restrict__ tmp,
                                                 int* __restrict__ rpd,
                                                 unsigned* __restrict__ epk) {
    __shared__ unsigned spk[CAP];        // 40960 B
    __shared__ unsigned char sd8[CAP];   // 10240 B
    __shared__ int cnt[256];
    __shared__ int pos[256];
    __shared__ int wsum[4];
    const int b = blockIdx.x;
    const int tid = threadIdx.x;
    const int beg = b * CAP;
    const int n = bcur[b];               // per-bucket count

    for (int i = tid; i < 256; i += 512) cnt[i] = 0;
    __syncthreads();
    for (int i = tid; i < n; i += 512) {
        int2 t = tmp[beg + i];
        spk[i] = (unsigned)t.x;
        int d8 = t.y & 255;
        sd8[i] = (unsigned char)d8;
        atomicAdd(&cnt[d8], 1);
    }
    __syncthreads();

    // 256-bin exclusive scan on first 4 waves
    if (tid < 256) {
        int v = cnt[tid];
        int lane = tid & 63, wid = tid >> 6;
        int s = v;
#pragma unroll
        for (int off = 1; off < 64; off <<= 1) {
            int t = __shfl_up(s, off, 64);
            if (lane >= off) s += t;
        }
        if (lane == 63) wsum[wid] = s;
        __syncthreads();
        int wbase = 0;
        for (int w = 0; w < wid; w++) wbase += wsum[w];
        int excl = wbase + s - v;
        pos[tid] = excl;
        int node = (b << 8) + tid;
        if (node < NODES) rpd[node] = (((beg << 1) + excl) << 8) | v;
    } else {
        __syncthreads();
    }
    __syncthreads();

    for (int i = tid; i < n; i += 512) {
        int p = atomicAdd(&pos[sd8[i]], 1);
        epk[(beg << 1) + p] = spk[i];
    }
}

// ---------------- aggregation: 1 node/wave, 4 subs x 16 lanes, fp16 pk_fma --
// Per edge: 16 lanes x uint4 = full 256-B fp16 row, consumed by v_pk_fma_f16
// with zero unpack instructions. Empirically pinned at ~104 us by random-
// gather miss concurrency (~3.9 TB/s fetch) -- traffic-insensitive +-15%.
__global__ __launch_bounds__(256) void aggregate(const int* __restrict__ rpd,
                                                 const unsigned* __restrict__ epack,
                                                 const unsigned short* __restrict__ hb,
                                                 const float* __restrict__ bias,
                                                 float* __restrict__ out) {
    const int lane = threadIdx.x & 63;
    const int node = blockIdx.x * 4 + (threadIdx.x >> 6);
    if (node >= NODES) return;
    const int sub = lane >> 4;       // 4 edge slots per wave
    const int li  = lane & 15;       // 16 lanes x 8 ch = 128 channels
    const int v = rpd[node];
    const int beg = (int)(((unsigned)v) >> 8);
    const int end = beg + (v & 255);
    const unsigned short* hp = hb + li * 8;

    h2 aA0 = (h2)0, aA1 = (h2)0, aA2 = (h2)0, aA3 = (h2)0;
    h2 aB0 = (h2)0, aB1 = (h2)0, aB2 = (h2)0, aB3 = (h2)0;

    for (int e0 = beg + sub; e0 < end; e0 += 16) {
        int i0 = e0, i1 = e0 + 4, i2 = e0 + 8, i3 = e0 + 12;
        unsigned p0 = epack[i0];                       // i0 < end guaranteed
        unsigned p1 = (i1 < end) ? epack[i1] : 0u;     // pk=0 -> val=0, src=0
        unsigned p2 = (i2 < end) ? epack[i2] : 0u;
        unsigned p3 = (i3 < end) ? epack[i3] : 0u;

        unsigned s0 = p0 & 0x1FFFFu, s1 = p1 & 0x1FFFFu;
        unsigned s2 = p2 & 0x1FFFFu, s3 = p3 & 0x1FFFFu;
        unsigned v0 = p0 >> 17, v1 = p1 >> 17, v2 = p2 >> 17, v3 = p3 >> 17;

        uint4 r0 = *(const uint4*)(hp + (size_t)s0 * D);
        uint4 r1 = *(const uint4*)(hp + (size_t)s1 * D);
        uint4 r2 = *(const uint4*)(hp + (size_t)s2 * D);
        uint4 r3 = *(const uint4*)(hp + (size_t)s3 * D);

        h2 w0 = uh2(v0 | (v0 << 16));
        h2 w1 = uh2(v1 | (v1 << 16));
        h2 w2 = uh2(v2 | (v2 << 16));
        h2 w3 = uh2(v3 | (v3 << 16));

        aA0 = uh2(r0.x) * w0 + aA0;
        aA1 = uh2(r0.y) * w0 + aA1;
        aA2 = uh2(r0.z) * w0 + aA2;
        aA3 = uh2(r0.w) * w0 + aA3;
        aB0 = uh2(r1.x) * w1 + aB0;
        aB1 = uh2(r1.y) * w1 + aB1;
        aB2 = uh2(r1.z) * w1 + aB2;
        aB3 = uh2(r1.w) * w1 + aB3;
        aA0 = uh2(r2.x) * w2 + aA0;
        aA1 = uh2(r2.y) * w2 + aA1;
        aA2 = uh2(r2.z) * w2 + aA2;
        aA3 = uh2(r2.w) * w2 + aA3;
        aB0 = uh2(r3.x) * w3 + aB0;
        aB1 = uh2(r3.y) * w3 + aB1;
        aB2 = uh2(r3.z) * w3 + aB2;
        aB3 = uh2(r3.w) * w3 + aB3;
    }

    // merge acc sets in fp16 (few-ulp partials), then f32 for the reduce
    h2 m0 = aA0 + aB0, m1 = aA1 + aB1, m2 = aA2 + aB2, m3 = aA3 + aB3;
    float r[8];
    r[0] = (float)m0[0]; r[1] = (float)m0[1];
    r[2] = (float)m1[0]; r[3] = (float)m1[1];
    r[4] = (float)m2[0]; r[5] = (float)m2[1];
    r[6] = (float)m3[0]; r[7] = (float)m3[1];
#pragma unroll
    for (int k = 0; k < 8; k++) {
        r[k] += __shfl_xor(r[k], 16, 64);
        r[k] += __shfl_xor(r[k], 32, 64);
    }

    if (sub == 0) {
        const float* bp = bias + li * 8;
        float4 b0 = *(const float4*)bp;
        float4 b1 = *(const float4*)(bp + 4);
        float4 o0, o1;
        o0.x = fmaxf(r[0] + b0.x, 0.f);
        o0.y = fmaxf(r[1] + b0.y, 0.f);
        o0.z = fmaxf(r[2] + b0.z, 0.f);
        o0.w = fmaxf(r[3] + b0.w, 0.f);
        o1.x = fmaxf(r[4] + b1.x, 0.f);
        o1.y = fmaxf(r[5] + b1.y, 0.f);
        o1.z = fmaxf(r[6] + b1.z, 0.f);
        o1.w = fmaxf(r[7] + b1.w, 0.f);
        float* op = out + (size_t)node * D + li * 8;
        *(float4*)op = o0;
        *(float4*)(op + 4) = o1;
    }
}

extern "C" void kernel_launch(void* const* d_in, const int* in_sizes, int n_in,
                              void* d_out, int out_size, void* d_ws, size_t ws_size,
                              hipStream_t stream) {
    const float* x    = (const float*)d_in[0];
    const int*   esrc = (const int*)  d_in[1];
    const int*   edst = (const int*)  d_in[2];
    const float* eval = (const float*)d_in[3];
    const float* w    = (const float*)d_in[4];
    const float* b    = (const float*)d_in[5];
    float* out = (float*)d_out;

    // workspace layout (bytes), total 58,065,664
    char* ws = (char*)d_ws;
    const size_t OFF_H    = 0;                       // 25,600,000 (fp16 h)
    const size_t OFF_WT   = 25600000;                // 32,768
    const size_t OFF_RPD  = OFF_WT   + 32768;        // 400,000 -> pad 400,128
    const size_t OFF_BCUR = OFF_RPD  + 400128;       // 2,048
    const size_t OFF_TMP  = OFF_BCUR + 2048;         // 391*CAP*8 = 32,030,720 (epack aliases)

    unsigned short* hb   = (unsigned short*)(ws + OFF_H);
    unsigned short* wt   = (unsigned short*)(ws + OFF_WT);
    int*            rpd  = (int*)           (ws + OFF_RPD);
    int*            bcur = (int*)           (ws + OFF_BCUR);
    int2*           tmp  = (int2*)          (ws + OFF_TMP);
    unsigned*       epk  = (unsigned*)      (ws + OFF_TMP);   // in-place alias

    hipMemsetAsync(bcur, 0, NBUCKET * sizeof(int), stream);
    wprep<<<64, 256, 0, stream>>>(w, wt);
    gemm_mfma<<<(NODES + 63) / 64, 256, 0, stream>>>(x, wt, hb);
    bin_pass1<<<NB_BIN, 512, 0, stream>>>(esrc, edst, eval, bcur, tmp);
    bin_pass2<<<NBUCKET, 512, 0, stream>>>(bcur, tmp, rpd, epk);
    aggregate<<<(NODES + 3) / 4, 256, 0, stream>>>(rpd, epk, hb, b, out);
}

// Round 7
// 285.997 us; speedup vs baseline: 9.8973x; 1.0259x over previous
//
#include <hip/hip_runtime.h>

#define NODES 100000
#define EDGES 3200000
#define D 128
#define NPB 196                          // nodes per bucket
#define NB2 512                          // buckets; 512 = 2*256CU -> perfectly balanced sort_agg
#define CH 4096                          // edges per binning block
#define NB_BIN ((EDGES + CH - 1) / CH)   // 782 binning blocks
#define CAP 7168                         // slots/bucket: mean 6272, sigma~79 -> +11 sigma
#define MAGIC196 175304788u              // floor(dst/196) = mulhi(dst, MAGIC196)>>3, dst<2^17

typedef unsigned short us8 __attribute__((ext_vector_type(8)));
typedef _Float16 half8 __attribute__((ext_vector_type(8)));
typedef _Float16 h2 __attribute__((ext_vector_type(2)));
typedef float f32x4 __attribute__((ext_vector_type(4)));

__device__ __forceinline__ unsigned short f32_to_f16_bits(float f) {
    return __builtin_bit_cast(unsigned short, (_Float16)f);
}
__device__ __forceinline__ h2 uh2(unsigned u) {
    return __builtin_bit_cast(h2, u);
}
__device__ __forceinline__ int div196(int dst) {
    return (int)(__umulhi((unsigned)dst, MAGIC196) >> 3);
}

// ---------------- w prep: fp32 [128][128] -> fp16 in B-fragment order -------
__global__ __launch_bounds__(256) void wprep(const float* __restrict__ w,
                                             unsigned short* __restrict__ wt) {
    int i = blockIdx.x * 256 + threadIdx.x;
    if (i >= 16384) return;
    int j  = i & 7;
    int l  = (i >> 3) & 63;
    int c  = (i >> 9) & 3;
    int ct = i >> 11;
    int k   = 32 * c + ((l >> 4) << 3) + j;
    int col = (ct << 4) + (l & 15);
    wt[i] = f32_to_f16_bits(w[k * D + col]);
}

// ---------------- GEMM via MFMA: h = fp16(x) @ fp16(w), hb fp16 row-major ---
__global__ __launch_bounds__(256) void gemm_mfma(const float* __restrict__ x,
                                                 const unsigned short* __restrict__ wt,
                                                 unsigned short* __restrict__ hb) {
    __shared__ unsigned short wl[16384];   // 32 KB
    const int tid = threadIdx.x;
    for (int i = tid; i < 2048; i += 256)
        ((us8*)wl)[i] = ((const us8*)wt)[i];
    __syncthreads();

    const int wave = tid >> 6, lane = tid & 63;
    const long r0 = ((long)blockIdx.x * 4 + wave) * 16;
    if (r0 >= NODES) return;
    const int m = lane & 15, q = lane >> 4;
    const float* xr = x + (r0 + m) * D;

    f32x4 acc[8];
#pragma unroll
    for (int ct = 0; ct < 8; ct++) acc[ct] = (f32x4){0.f, 0.f, 0.f, 0.f};

#pragma unroll
    for (int c = 0; c < 4; c++) {
        const int k0 = 32 * c + 8 * q;
        float4 xa = *(const float4*)(xr + k0);
        float4 xb = *(const float4*)(xr + k0 + 4);
        half8 a;
        a[0] = (_Float16)xa.x;
        a[1] = (_Float16)xa.y;
        a[2] = (_Float16)xa.z;
        a[3] = (_Float16)xa.w;
        a[4] = (_Float16)xb.x;
        a[5] = (_Float16)xb.y;
        a[6] = (_Float16)xb.z;
        a[7] = (_Float16)xb.w;
#pragma unroll
        for (int ct = 0; ct < 8; ct++) {
            half8 bfr = *(const half8*)&wl[(((ct << 2) + c) * 64 + lane) * 8];
            acc[ct] = __builtin_amdgcn_mfma_f32_16x16x32_f16(a, bfr, acc[ct], 0, 0, 0);
        }
    }

    // C/D: col = lane&15, row = (lane>>4)*4 + reg
#pragma unroll
    for (int ct = 0; ct < 8; ct++) {
#pragma unroll
        for (int r = 0; r < 4; r++) {
            int row = q * 4 + r;
            hb[(r0 + row) * D + ct * 16 + m] = f32_to_f16_bits(acc[ct][r]);
        }
    }
}

// ---------------- pass 1: SINGLE global read, register-staged counting sort -
// 512 threads x 8 edges in registers; hist; LDS scatter sorted by bucket;
// run-contiguous writeout. Record y = (bk<<8)|d8 (bk<512, d8<196).
// pk = (fp16_bits(val) << 17) | src   (val in [0,1) -> bits < 0x3C00 < 2^15)
__global__ __launch_bounds__(512) void bin_pass1(const int* __restrict__ esrc,
                                                 const int* __restrict__ edst,
                                                 const float* __restrict__ eval,
                                                 int* __restrict__ bcur,
                                                 int2* __restrict__ tmp) {
    __shared__ int2 sed[CH];          // 32768 B sorted (pk, (bk<<8)|d8)
    __shared__ int hist[NB2];         // 2048 B
    __shared__ int basel[NB2];
    __shared__ int lcur[NB2];
    __shared__ int gbase[NB2];
    __shared__ int wsum[8];
    const int tid = threadIdx.x;
    const long e0 = (long)blockIdx.x * CH;
    const int n = (int)((EDGES - e0 < CH) ? (EDGES - e0) : CH);

    for (int bk = tid; bk < NB2; bk += 512) { hist[bk] = 0; lcur[bk] = 0; }
    __syncthreads();

    // one coalesced pass: stage 8 edges/thread in registers + histogram
    unsigned pk[8];
    int ds[8];
#pragma unroll
    for (int u = 0; u < 8; u++) {
        int i = tid + u * 512;
        if (i < n) {
            long e = e0 + i;
            int dst = edst[e];
            int bk = div196(dst);
            int d8 = dst - bk * NPB;
            unsigned hv = (unsigned)f32_to_f16_bits(eval[e]);
            pk[u] = (hv << 17) | (unsigned)esrc[e];
            ds[u] = (bk << 8) | d8;
            atomicAdd(&hist[bk], 1);
        } else {
            ds[u] = -1;
        }
    }
    __syncthreads();

    // pairwise exclusive scan of 512 bins: thread t<256 owns bins 2t, 2t+1
    int h0 = 0, h1 = 0;
    if (tid < 256) { h0 = hist[2 * tid]; h1 = hist[2 * tid + 1]; }
    int s = h0 + h1;
    int lane = tid & 63, wid = tid >> 6;
    int sc = s;
#pragma unroll
    for (int off = 1; off < 64; off <<= 1) {
        int t = __shfl_up(sc, off, 64);
        if (lane >= off) sc += t;
    }
    if (lane == 63) wsum[wid] = sc;
    __syncthreads();
    int wb = 0;
    for (int w2 = 0; w2 < wid && w2 < 4; w2++) wb += wsum[w2];
    int excl = wb + sc - s;
    if (tid < 256) { basel[2 * tid] = excl; basel[2 * tid + 1] = excl + h0; }
    for (int bk = tid; bk < NB2; bk += 512) {
        int c = hist[bk];
        if (c > 0) gbase[bk] = bk * CAP + atomicAdd(&bcur[bk], c);
    }
    __syncthreads();

    // scatter from registers into LDS, sorted by bucket
#pragma unroll
    for (int u = 0; u < 8; u++) {
        if (ds[u] >= 0) {
            int bk = ds[u] >> 8;
            int lp = basel[bk] + atomicAdd(&lcur[bk], 1);
            sed[lp] = make_int2((int)pk[u], ds[u]);
        }
    }
    __syncthreads();

    // coalesced write-out: consecutive i -> consecutive global within runs
    for (int i = tid; i < n; i += 512) {
        int2 t = sed[i];
        int bk = t.y >> 8;
        tmp[gbase[bk] + (i - basel[bk])] = t;
    }
}

// ---------------- sort_agg: pass2 + aggregate fused, one block per bucket ---
// 512 blocks = exactly 2/CU, all resident, per-CU load = 12.5K edges (same as
// the proven 104-us gather plateau). Phase A: hist (reads tmp.y only) -> 256-
// bin scan -> CSR pos[] -> scatter pk into node-sorted LDS. Phase B: per-wave
// register fp16 pk-fma gather (edge records now read from LDS, faster than the
// old global epack). Deletes epack/rpd round-trip (25.6 MB) and one launch.
__global__ __launch_bounds__(512) void sort_agg(const int* __restrict__ bcur,
                                                const int2* __restrict__ tmp,
                                                const unsigned short* __restrict__ hb,
                                                const float* __restrict__ bias,
                                                float* __restrict__ out) {
    __shared__ unsigned spk[CAP];        // 28672 B node-sorted pk
    __shared__ int cnt[256];
    __shared__ int pos[257];
    __shared__ int cur[256];
    __shared__ int wsum[4];
    const int tid = threadIdx.x;
    const int b = blockIdx.x;
    const int n = bcur[b];
    const long base = (long)b * CAP;
    const int lane = tid & 63, wid = tid >> 6;

    if (tid < 256) cnt[tid] = 0;
    __syncthreads();
    // A1: histogram node-in-bucket (4-byte read of .y only)
    for (int i = tid; i < n; i += 512)
        atomicAdd(&cnt[tmp[base + i].y & 255], 1);
    __syncthreads();

    // 256-bin exclusive scan on waves 0-3 (no divergent barrier)
    int v = 0, s = 0;
    if (tid < 256) {
        v = cnt[tid];
        s = v;
#pragma unroll
        for (int off = 1; off < 64; off <<= 1) {
            int t = __shfl_up(s, off, 64);
            if (lane >= off) s += t;
        }
        if (lane == 63) wsum[wid] = s;
    }
    __syncthreads();
    if (tid < 256) {
        int wb = 0;
        for (int w2 = 0; w2 < wid; w2++) wb += wsum[w2];
        int excl = wb + s - v;
        pos[tid] = excl;
        cur[tid] = excl;
        if (tid == 255) pos[256] = excl + v;
    }
    __syncthreads();

    // A2: scatter pk into node-sorted LDS
    for (int i = tid; i < n; i += 512) {
        int2 t = tmp[base + i];
        int p = atomicAdd(&cur[t.y & 255], 1);
        spk[p] = (unsigned)t.x;
    }
    __syncthreads();

    // B: 8 waves, nodes stride-8; 4 subs x 16 lanes, fp16 pk_fma (proven loop)
    const int sub = lane >> 4, li = lane & 15;
    const unsigned short* hp = hb + li * 8;
    const float* bp = bias + li * 8;
    const float4 b0 = *(const float4*)bp;
    const float4 b1 = *(const float4*)(bp + 4);

    for (int nd = wid; nd < NPB; nd += 8) {
        int node = b * NPB + nd;
        if (node >= NODES) break;          // node increases with nd
        const int beg = pos[nd], end = pos[nd + 1];

        h2 aA0 = (h2)0, aA1 = (h2)0, aA2 = (h2)0, aA3 = (h2)0;
        h2 aB0 = (h2)0, aB1 = (h2)0, aB2 = (h2)0, aB3 = (h2)0;

        for (int e0 = beg + sub; e0 < end; e0 += 16) {
            int i0 = e0, i1 = e0 + 4, i2 = e0 + 8, i3 = e0 + 12;
            unsigned p0 = spk[i0];                       // i0 < end guaranteed
            unsigned p1 = (i1 < end) ? spk[i1] : 0u;     // pk=0 -> val=0, src=0
            unsigned p2 = (i2 < end) ? spk[i2] : 0u;
            unsigned p3 = (i3 < end) ? spk[i3] : 0u;

            unsigned s0 = p0 & 0x1FFFFu, s1 = p1 & 0x1FFFFu;
            unsigned s2 = p2 & 0x1FFFFu, s3 = p3 & 0x1FFFFu;
            unsigned v0 = p0 >> 17, v1 = p1 >> 17, v2 = p2 >> 17, v3 = p3 >> 17;

            uint4 r0 = *(const uint4*)(hp + (size_t)s0 * D);
            uint4 r1 = *(const uint4*)(hp + (size_t)s1 * D);
            uint4 r2 = *(const uint4*)(hp + (size_t)s2 * D);
            uint4 r3 = *(const uint4*)(hp + (size_t)s3 * D);

            h2 w0 = uh2(v0 | (v0 << 16));
            h2 w1 = uh2(v1 | (v1 << 16));
            h2 w2 = uh2(v2 | (v2 << 16));
            h2 w3 = uh2(v3 | (v3 << 16));

            aA0 = uh2(r0.x) * w0 + aA0;
            aA1 = uh2(r0.y) * w0 + aA1;
            aA2 = uh2(r0.z) * w0 + aA2;
            aA3 = uh2(r0.w) * w0 + aA3;
            aB0 = uh2(r1.x) * w1 + aB0;
            aB1 = uh2(r1.y) * w1 + aB1;
            aB2 = uh2(r1.z) * w1 + aB2;
            aB3 = uh2(r1.w) * w1 + aB3;
            aA0 = uh2(r2.x) * w2 + aA0;
            aA1 = uh2(r2.y) * w2 + aA1;
            aA2 = uh2(r2.z) * w2 + aA2;
            aA3 = uh2(r2.w) * w2 + aA3;
            aB0 = uh2(r3.x) * w3 + aB0;
            aB1 = uh2(r3.y) * w3 + aB1;
            aB2 = uh2(r3.z) * w3 + aB2;
            aB3 = uh2(r3.w) * w3 + aB3;
        }

        // merge acc sets in fp16 (few-ulp partials), then f32 for the reduce
        h2 m0 = aA0 + aB0, m1 = aA1 + aB1, m2 = aA2 + aB2, m3 = aA3 + aB3;
        float r[8];
        r[0] = (float)m0[0]; r[1] = (float)m0[1];
        r[2] = (float)m1[0]; r[3] = (float)m1[1];
        r[4] = (float)m2[0]; r[5] = (float)m2[1];
        r[6] = (float)m3[0]; r[7] = (float)m3[1];
#pragma unroll
        for (int k = 0; k < 8; k++) {
            r[k] += __shfl_xor(r[k], 16, 64);
            r[k] += __shfl_xor(r[k], 32, 64);
        }

        if (sub == 0) {
            float4 o0, o1;
            o0.x = fmaxf(r[0] + b0.x, 0.f);
            o0.y = fmaxf(r[1] + b0.y, 0.f);
            o0.z = fmaxf(r[2] + b0.z, 0.f);
            o0.w = fmaxf(r[3] + b0.w, 0.f);
            o1.x = fmaxf(r[4] + b1.x, 0.f);
            o1.y = fmaxf(r[5] + b1.y, 0.f);
            o1.z = fmaxf(r[6] + b1.z, 0.f);
            o1.w = fmaxf(r[7] + b1.w, 0.f);
            float* op = out + (size_t)node * D + li * 8;
            *(float4*)op = o0;
            *(float4*)(op + 4) = o1;
        }
    }
}

extern "C" void kernel_launch(void* const* d_in, const int* in_sizes, int n_in,
                              void* d_out, int out_size, void* d_ws, size_t ws_size,
                              hipStream_t stream) {
    const float* x    = (const float*)d_in[0];
    const int*   esrc = (const int*)  d_in[1];
    const int*   edst = (const int*)  d_in[2];
    const float* eval = (const float*)d_in[3];
    const float* w    = (const float*)d_in[4];
    const float* b    = (const float*)d_in[5];
    float* out = (float*)d_out;

    // workspace layout (bytes), total 54,995,072
    char* ws = (char*)d_ws;
    const size_t OFF_H    = 0;                       // 25,600,000 (fp16 h)
    const size_t OFF_WT   = 25600000;                // 32,768
    const size_t OFF_BCUR = OFF_WT   + 32768;        // 2,048 (512 ints)
    const size_t OFF_TMP  = OFF_BCUR + 2048;         // 512*CAP*8 = 29,360,128

    unsigned short* hb   = (unsigned short*)(ws + OFF_H);
    unsigned short* wt   = (unsigned short*)(ws + OFF_WT);
    int*            bcur = (int*)           (ws + OFF_BCUR);
    int2*           tmp  = (int2*)          (ws + OFF_TMP);

    hipMemsetAsync(bcur, 0, NB2 * sizeof(int), stream);
    wprep<<<64, 256, 0, stream>>>(w, wt);
    gemm_mfma<<<(NODES + 63) / 64, 256, 0, stream>>>(x, wt, hb);
    bin_pass1<<<NB_BIN, 512, 0, stream>>>(esrc, edst, eval, bcur, tmp);
    sort_agg<<<NB2, 512, 0, stream>>>(bcur, tmp, hb, b, out);
}

// Round 8
// 280.267 us; speedup vs baseline: 10.0996x; 1.0204x over previous
//
#include <hip/hip_runtime.h>

#define NODES 100000
#define EDGES 3200000
#define D 128
#define NPB 196                          // nodes per bucket
#define NB2 512                          // buckets; 512 = 2*256CU -> balanced sort_agg
#define CH 8192                          // edges per binning block
#define NB_BIN ((EDGES + CH - 1) / CH)   // 391 binning blocks
#define CAP 7168                         // slots/bucket: mean 6272, sigma~79 -> +11 sigma
#define MAGIC196 175304788u              // floor(dst/196) = mulhi(dst, MAGIC196)>>3, dst<2^17
#define NBIN2 (NPB * 8)                  // 1568 (node, src-chunk) bins in sort_agg

typedef unsigned short us8 __attribute__((ext_vector_type(8)));
typedef _Float16 half8 __attribute__((ext_vector_type(8)));
typedef _Float16 h2 __attribute__((ext_vector_type(2)));
typedef float f32x4 __attribute__((ext_vector_type(4)));

__device__ __forceinline__ unsigned short f32_to_f16_bits(float f) {
    return __builtin_bit_cast(unsigned short, (_Float16)f);
}
__device__ __forceinline__ h2 uh2(unsigned u) {
    return __builtin_bit_cast(h2, u);
}
__device__ __forceinline__ int div196(int dst) {
    return (int)(__umulhi((unsigned)dst, MAGIC196) >> 3);
}

// ---------------- GEMM via MFMA: h = fp16(x) @ fp16(w), hb fp16 row-major ---
// w converted fp32->fp16 into LDS inline (wprep kernel deleted; w is 64 KB,
// L2-hot broadcast -- proven harmless in the r4 fused variant). 8 waves/block.
__global__ __launch_bounds__(512) void gemm_mfma(const float* __restrict__ x,
                                                 const float* __restrict__ w,
                                                 unsigned short* __restrict__ hb) {
    __shared__ unsigned short wl[16384];   // 32 KB
    const int tid = threadIdx.x;
    // wl[((ct*4+c)*64+l)*8+j] = f16(w[(32c+(l>>4)*8+j)][16ct+(l&15)])
    for (int i = tid; i < 16384; i += 512) {
        int j  = i & 7;
        int l  = (i >> 3) & 63;
        int c  = (i >> 9) & 3;
        int ct = i >> 11;
        int k   = 32 * c + ((l >> 4) << 3) + j;
        int col = (ct << 4) + (l & 15);
        wl[i] = f32_to_f16_bits(w[k * D + col]);
    }
    __syncthreads();

    const int wave = tid >> 6, lane = tid & 63;
    const long r0 = ((long)blockIdx.x * 8 + wave) * 16;
    if (r0 >= NODES) return;
    const int m = lane & 15, q = lane >> 4;
    const float* xr = x + (r0 + m) * D;

    f32x4 acc[8];
#pragma unroll
    for (int ct = 0; ct < 8; ct++) acc[ct] = (f32x4){0.f, 0.f, 0.f, 0.f};

#pragma unroll
    for (int c = 0; c < 4; c++) {
        const int k0 = 32 * c + 8 * q;
        float4 xa = *(const float4*)(xr + k0);
        float4 xb = *(const float4*)(xr + k0 + 4);
        half8 a;
        a[0] = (_Float16)xa.x;
        a[1] = (_Float16)xa.y;
        a[2] = (_Float16)xa.z;
        a[3] = (_Float16)xa.w;
        a[4] = (_Float16)xb.x;
        a[5] = (_Float16)xb.y;
        a[6] = (_Float16)xb.z;
        a[7] = (_Float16)xb.w;
#pragma unroll
        for (int ct = 0; ct < 8; ct++) {
            half8 bfr = *(const half8*)&wl[(((ct << 2) + c) * 64 + lane) * 8];
            acc[ct] = __builtin_amdgcn_mfma_f32_16x16x32_f16(a, bfr, acc[ct], 0, 0, 0);
        }
    }

    // C/D: col = lane&15, row = (lane>>4)*4 + reg
#pragma unroll
    for (int ct = 0; ct < 8; ct++) {
#pragma unroll
        for (int r = 0; r < 4; r++) {
            int row = q * 4 + r;
            hb[(r0 + row) * D + ct * 16 + m] = f32_to_f16_bits(acc[ct][r]);
        }
    }
}

// ---------------- pass 1: SINGLE global read, register-staged counting sort -
// 512 threads x 16 edges in registers; hist; LDS scatter sorted by bucket;
// run-contiguous writeout (runs avg 16 edges = 128 B -> line-granular stores).
// Record y = (bk<<8)|d8 (bk<512, d8<196). bcur holds per-bucket COUNTS.
// pk = (fp16_bits(val) << 17) | src   (val in [0,1) -> bits < 0x3C00 < 2^15)
__global__ __launch_bounds__(512) void bin_pass1(const int* __restrict__ esrc,
                                                 const int* __restrict__ edst,
                                                 const float* __restrict__ eval,
                                                 int* __restrict__ bcur,
                                                 int2* __restrict__ tmp) {
    __shared__ int2 sed[CH];          // 65536 B sorted (pk, (bk<<8)|d8)
    __shared__ int hist[NB2];         // 2048 B
    __shared__ int basel[NB2];
    __shared__ int lcur[NB2];
    __shared__ int gbase[NB2];
    __shared__ int wsum[8];
    const int tid = threadIdx.x;
    const long e0 = (long)blockIdx.x * CH;
    const int n = (int)((EDGES - e0 < CH) ? (EDGES - e0) : CH);

    for (int bk = tid; bk < NB2; bk += 512) { hist[bk] = 0; lcur[bk] = 0; }
    __syncthreads();

    // one coalesced pass: stage 16 edges/thread in registers + histogram
    unsigned pk[16];
    int ds[16];
#pragma unroll
    for (int u = 0; u < 16; u++) {
        int i = tid + u * 512;
        if (i < n) {
            long e = e0 + i;
            int dst = edst[e];
            int bk = div196(dst);
            int d8 = dst - bk * NPB;
            unsigned hv = (unsigned)f32_to_f16_bits(eval[e]);
            pk[u] = (hv << 17) | (unsigned)esrc[e];
            ds[u] = (bk << 8) | d8;
            atomicAdd(&hist[bk], 1);
        } else {
            ds[u] = -1;
        }
    }
    __syncthreads();

    // pairwise exclusive scan of 512 bins: thread t<256 owns bins 2t, 2t+1
    int h0 = 0, h1 = 0;
    if (tid < 256) { h0 = hist[2 * tid]; h1 = hist[2 * tid + 1]; }
    int s = h0 + h1;
    int lane = tid & 63, wid = tid >> 6;
    int sc = s;
#pragma unroll
    for (int off = 1; off < 64; off <<= 1) {
        int t = __shfl_up(sc, off, 64);
        if (lane >= off) sc += t;
    }
    if (lane == 63) wsum[wid] = sc;
    __syncthreads();
    int wb = 0;
    for (int w2 = 0; w2 < wid && w2 < 4; w2++) wb += wsum[w2];
    int excl = wb + sc - s;
    if (tid < 256) { basel[2 * tid] = excl; basel[2 * tid + 1] = excl + h0; }
    for (int bk = tid; bk < NB2; bk += 512) {
        int c = hist[bk];
        if (c > 0) gbase[bk] = bk * CAP + atomicAdd(&bcur[bk], c);
    }
    __syncthreads();

    // scatter from registers into LDS, sorted by bucket
#pragma unroll
    for (int u = 0; u < 16; u++) {
        if (ds[u] >= 0) {
            int bk = ds[u] >> 8;
            int lp = basel[bk] + atomicAdd(&lcur[bk], 1);
            sed[lp] = make_int2((int)pk[u], ds[u]);
        }
    }
    __syncthreads();

    // coalesced write-out: consecutive i -> consecutive global within runs
    for (int i = tid; i < n; i += 512) {
        int2 t = sed[i];
        int bk = t.y >> 8;
        tmp[gbase[bk] + (i - basel[bk])] = t;
    }
}

// ---------------- sort_agg: bucket sort + aggregate, one block per bucket ---
// Phase A bins edges by key = (node_in_bucket<<3) | (src>>14): per-node lists
// become SRC-CHUNK-GROUPED (16K-node chunks = 3.2 MB < 4-MB XCD L2). All waves
// sweep chunks in ascending order -> per-XCD gather working set at any instant
// ~ one chunk -> L2 hit rate up (57% -> ~75% predicted), cutting avg MSHR
// occupancy. Phase B: proven register fp16 pk-fma gather loop.
__global__ __launch_bounds__(512) void sort_agg(const int* __restrict__ bcur,
                                                const int2* __restrict__ tmp,
                                                const unsigned short* __restrict__ hb,
                                                const float* __restrict__ bias,
                                                float* __restrict__ out) {
    __shared__ unsigned spk[CAP];        // 28672 B chunk-grouped node-sorted pk
    __shared__ int hist[NBIN2];          // 6272 B (cursors after scan)
    __shared__ int pos[NPB + 1];         // per-node CSR
    __shared__ int wsum[8];
    const int tid = threadIdx.x;
    const int b = blockIdx.x;
    const int n = bcur[b];
    const long base = (long)b * CAP;
    const int lane = tid & 63, wid = tid >> 6;

    for (int i = tid; i < NBIN2; i += 512) hist[i] = 0;
    __syncthreads();

    // A1: histogram by (node, src-chunk)
    for (int i = tid; i < n; i += 512) {
        int2 t = tmp[base + i];
        int key = ((t.y & 255) << 3) | ((t.x & 0x1FFFF) >> 14);
        atomicAdd(&hist[key], 1);
    }
    __syncthreads();

    // exclusive scan of 1568 bins: thread t owns bins 4t..4t+3
    int h[4];
    int s = 0;
#pragma unroll
    for (int u = 0; u < 4; u++) {
        int bi = tid * 4 + u;
        h[u] = (bi < NBIN2) ? hist[bi] : 0;
        s += h[u];
    }
    int sc = s;
#pragma unroll
    for (int off = 1; off < 64; off <<= 1) {
        int t = __shfl_up(sc, off, 64);
        if (lane >= off) sc += t;
    }
    if (lane == 63) wsum[wid] = sc;
    __syncthreads();
    int wb = 0;
    for (int w2 = 0; w2 < wid; w2++) wb += wsum[w2];
    int run = wb + sc - s;               // exclusive prefix of this thread's 4 bins
#pragma unroll
    for (int u = 0; u < 4; u++) {
        int bi = tid * 4 + u;
        if (bi < NBIN2) hist[bi] = run;  // becomes scatter cursor
        run += h[u];
    }
    __syncthreads();
    // capture per-node bases BEFORE scatter mutates cursors
    if (tid < NPB) pos[tid] = hist[tid << 3];
    if (tid == NPB) pos[NPB] = n;
    __syncthreads();

    // A2: scatter pk into chunk-grouped, node-sorted LDS (tmp re-read is L2-hot)
    for (int i = tid; i < n; i += 512) {
        int2 t = tmp[base + i];
        int key = ((t.y & 255) << 3) | ((t.x & 0x1FFFF) >> 14);
        int p = atomicAdd(&hist[key], 1);
        spk[p] = (unsigned)t.x;
    }
    __syncthreads();

    // B: 8 waves, nodes stride-8; 4 subs x 16 lanes, fp16 pk_fma (proven loop)
    const int sub = lane >> 4, li = lane & 15;
    const unsigned short* hp = hb + li * 8;
    const float* bp = bias + li * 8;
    const float4 b0 = *(const float4*)bp;
    const float4 b1 = *(const float4*)(bp + 4);

    for (int nd = wid; nd < NPB; nd += 8) {
        int node = b * NPB + nd;
        if (node >= NODES) break;          // node increases with nd
        const int beg = pos[nd], end = pos[nd + 1];

        h2 aA0 = (h2)0, aA1 = (h2)0, aA2 = (h2)0, aA3 = (h2)0;
        h2 aB0 = (h2)0, aB1 = (h2)0, aB2 = (h2)0, aB3 = (h2)0;

        for (int e0 = beg + sub; e0 < end; e0 += 16) {
            int i0 = e0, i1 = e0 + 4, i2 = e0 + 8, i3 = e0 + 12;
            unsigned p0 = spk[i0];                       // i0 < end guaranteed
            unsigned p1 = (i1 < end) ? spk[i1] : 0u;     // pk=0 -> val=0, src=0
            unsigned p2 = (i2 < end) ? spk[i2] : 0u;
            unsigned p3 = (i3 < end) ? spk[i3] : 0u;

            unsigned s0 = p0 & 0x1FFFFu, s1 = p1 & 0x1FFFFu;
            unsigned s2 = p2 & 0x1FFFFu, s3 = p3 & 0x1FFFFu;
            unsigned v0 = p0 >> 17, v1 = p1 >> 17, v2 = p2 >> 17, v3 = p3 >> 17;

            uint4 r0 = *(const uint4*)(hp + (size_t)s0 * D);
            uint4 r1 = *(const uint4*)(hp + (size_t)s1 * D);
            uint4 r2 = *(const uint4*)(hp + (size_t)s2 * D);
            uint4 r3 = *(const uint4*)(hp + (size_t)s3 * D);

            h2 w0 = uh2(v0 | (v0 << 16));
            h2 w1 = uh2(v1 | (v1 << 16));
            h2 w2 = uh2(v2 | (v2 << 16));
            h2 w3 = uh2(v3 | (v3 << 16));

            aA0 = uh2(r0.x) * w0 + aA0;
            aA1 = uh2(r0.y) * w0 + aA1;
            aA2 = uh2(r0.z) * w0 + aA2;
            aA3 = uh2(r0.w) * w0 + aA3;
            aB0 = uh2(r1.x) * w1 + aB0;
            aB1 = uh2(r1.y) * w1 + aB1;
            aB2 = uh2(r1.z) * w1 + aB2;
            aB3 = uh2(r1.w) * w1 + aB3;
            aA0 = uh2(r2.x) * w2 + aA0;
            aA1 = uh2(r2.y) * w2 + aA1;
            aA2 = uh2(r2.z) * w2 + aA2;
            aA3 = uh2(r2.w) * w2 + aA3;
            aB0 = uh2(r3.x) * w3 + aB0;
            aB1 = uh2(r3.y) * w3 + aB1;
            aB2 = uh2(r3.z) * w3 + aB2;
            aB3 = uh2(r3.w) * w3 + aB3;
        }

        // merge acc sets in fp16 (few-ulp partials), then f32 for the reduce
        h2 m0 = aA0 + aB0, m1 = aA1 + aB1, m2 = aA2 + aB2, m3 = aA3 + aB3;
        float r[8];
        r[0] = (float)m0[0]; r[1] = (float)m0[1];
        r[2] = (float)m1[0]; r[3] = (float)m1[1];
        r[4] = (float)m2[0]; r[5] = (float)m2[1];
        r[6] = (float)m3[0]; r[7] = (float)m3[1];
#pragma unroll
        for (int k = 0; k < 8; k++) {
            r[k] += __shfl_xor(r[k], 16, 64);
            r[k] += __shfl_xor(r[k], 32, 64);
        }

        if (sub == 0) {
            float4 o0, o1;
            o0.x = fmaxf(r[0] + b0.x, 0.f);
            o0.y = fmaxf(r[1] + b0.y, 0.f);
            o0.z = fmaxf(r[2] + b0.z, 0.f);
            o0.w = fmaxf(r[3] + b0.w, 0.f);
            o1.x = fmaxf(r[4] + b1.x, 0.f);
            o1.y = fmaxf(r[5] + b1.y, 0.f);
            o1.z = fmaxf(r[6] + b1.z, 0.f);
            o1.w = fmaxf(r[7] + b1.w, 0.f);
            float* op = out + (size_t)node * D + li * 8;
            *(float4*)op = o0;
            *(float4*)(op + 4) = o1;
        }
    }
}

extern "C" void kernel_launch(void* const* d_in, const int* in_sizes, int n_in,
                              void* d_out, int out_size, void* d_ws, size_t ws_size,
                              hipStream_t stream) {
    const float* x    = (const float*)d_in[0];
    const int*   esrc = (const int*)  d_in[1];
    const int*   edst = (const int*)  d_in[2];
    const float* eval = (const float*)d_in[3];
    const float* w    = (const float*)d_in[4];
    const float* b    = (const float*)d_in[5];
    float* out = (float*)d_out;

    // workspace layout (bytes), total 54,962,176
    char* ws = (char*)d_ws;
    const size_t OFF_H    = 0;                       // 25,600,000 (fp16 h)
    const size_t OFF_BCUR = 25600000;                // 2,048 (512 ints)
    const size_t OFF_TMP  = OFF_BCUR + 2048;         // 512*CAP*8 = 29,360,128

    unsigned short* hb   = (unsigned short*)(ws + OFF_H);
    int*            bcur = (int*)           (ws + OFF_BCUR);
    int2*           tmp  = (int2*)          (ws + OFF_TMP);

    hipMemsetAsync(bcur, 0, NB2 * sizeof(int), stream);
    gemm_mfma<<<(NODES + 127) / 128, 512, 0, stream>>>(x, w, hb);
    bin_pass1<<<NB_BIN, 512, 0, stream>>>(esrc, edst, eval, bcur, tmp);
    sort_agg<<<NB2, 512, 0, stream>>>(bcur, tmp, hb, b, out);
}